// Round 5
// baseline (630.799 us; speedup 1.0000x reference)
//
#include <hip/hip_runtime.h>
#include <hip/hip_bf16.h>

using f32x4 = __attribute__((ext_vector_type(4))) float;
using bf16x8 = __attribute__((ext_vector_type(8))) short;

#define DEVI __device__ __forceinline__

DEVI short f2bf(float f) { __hip_bfloat16 h = __float2bfloat16(f); return *reinterpret_cast<short*>(&h); }
DEVI unsigned int pk2(float a, float b) {
    float2 t; t.x = a; t.y = b;
    __hip_bfloat162 h = __float22bfloat162_rn(t);
    return *reinterpret_cast<unsigned int*>(&h);
}
DEVI float bf2f(unsigned short s) { unsigned int u = ((unsigned int)s) << 16; return __uint_as_float(u); }

constexpr int NB = 8192;   // windows
constexpr int NT = 49;     // tokens per window
constexpr int CD = 128;    // channels
constexpr float SCALE = 0.17677669529663687f; // 32^-0.5
constexpr float LOG2E = 1.4426950408889634f;

// ---- ws layout (bytes) ----
constexpr size_t WS_QKVWT  = 0;        // 384*128 bf16 = 98304
constexpr size_t WS_PROJWT = 98304;    // 128*128 bf16 = 32768
constexpr size_t WS_BIAS   = 131072;   // 4*2401 bf16  = 19208
constexpr size_t WS_QKV    = 150528;   // 3 * 8192*4*49*32 bf16
constexpr size_t SQKV      = (size_t)NB * 4 * NT * 32;      // shorts per q/k/v plane
constexpr size_t WS_SPLIT_NEED = WS_QKV + 3 * SQKV * 2;     // ~308.4 MB

__global__ __launch_bounds__(256) void prep_kernel(
    const float* __restrict__ qkv_w, const float* __restrict__ proj_w,
    const float* __restrict__ rbt, const int* __restrict__ rel_index,
    short* __restrict__ qkvwT, short* __restrict__ projwT, unsigned short* __restrict__ biasBf)
{
    int i = blockIdx.x * 256 + threadIdx.x;
    if (i < 384 * 128) { int j = i >> 7, k = i & 127; qkvwT[i] = f2bf(qkv_w[k * 384 + j]); }
    if (i < 128 * 128) { int j = i >> 7, k = i & 127; projwT[i] = f2bf(proj_w[k * 128 + j]); }
    if (i < 4 * NT * NT) { int h = i / (NT * NT); int t = i % (NT * NT); biasBf[i] = (unsigned short)f2bf(rbt[rel_index[t] * 4 + h]); }
}

// swizzled index into a [64][128] bf16 tile
DEVI int swz128(int row, int col) { return row * 128 + (col ^ ((row & 7) << 3)); }

// ============================================================================
// Kernel A: QKV GEMM.  qkv[s][b][h][t][d] bf16, q pre-scaled.
// grid = 401408/64 = 6272 blocks x 256 thr; wave w owns rows m0+16w..+16.
// ============================================================================
__global__ __launch_bounds__(256) void qkv_gemm_kernel(
    const float* __restrict__ x, const float* __restrict__ qkv_b,
    const short* __restrict__ qkvwT, short* __restrict__ qkv)
{
    const int tid = threadIdx.x;
    const int w = tid >> 6, lane = tid & 63, lr = lane & 15, lg = lane >> 4;
    const unsigned m0 = blockIdx.x * 64 + 16 * w;     // wave row base (all rows valid)

    // A-fragments direct from global
    bf16x8 a[4];
    {
        const float* xrow = x + (size_t)(m0 + lr) * CD;
#pragma unroll
        for (int kt = 0; kt < 4; ++kt) {
            const float4* p = reinterpret_cast<const float4*>(xrow + kt * 32 + lg * 8);
            float4 v0 = p[0], v1 = p[1];
            union { unsigned int u[4]; bf16x8 v; } cv;
            cv.u[0] = pk2(v0.x, v0.y); cv.u[1] = pk2(v0.z, v0.w);
            cv.u[2] = pk2(v1.x, v1.y); cv.u[3] = pk2(v1.z, v1.w);
            a[kt] = cv.v;
        }
    }

    // per-r store base: row -> (b,t);  base32 = b*6272 + t*32 + lr
    unsigned base32[4];
#pragma unroll
    for (int r = 0; r < 4; ++r) {
        unsigned grow = m0 + 4 * lg + r;
        unsigned bI = (unsigned)(((unsigned long long)grow * 2804876602ull) >> 37); // exact /49
        unsigned tI = grow - bI * 49;
        base32[r] = bI * 6272u + tI * 32u + lr;
    }

#pragma unroll
    for (int nt = 0; nt < 24; ++nt) {
        f32x4 acc = {0.f, 0.f, 0.f, 0.f};
#pragma unroll
        for (int kt = 0; kt < 4; ++kt) {
            bf16x8 bb = *reinterpret_cast<const bf16x8*>(&qkvwT[(nt * 16 + lr) * 128 + kt * 32 + lg * 8]);
            acc = __builtin_amdgcn_mfma_f32_16x16x32_bf16(a[kt], bb, acc, 0, 0, 0);
        }
        const int s = nt >> 3;             // 0=q 1=k 2=v
        const int h = (nt >> 1) & 3;
        const int d0 = (nt & 1) * 16;
        const float bias = qkv_b[nt * 16 + lr];
        const float scl = (s == 0) ? SCALE : 1.0f;
        short* dst = qkv + (size_t)s * SQKV + (size_t)h * (NT * 32) + d0;
#pragma unroll
        for (int r = 0; r < 4; ++r)
            dst[base32[r]] = f2bf((acc[r] + bias) * scl);
    }
}

// ============================================================================
// Kernel B: attention + proj.  1 block = 1 window, 4 waves, wave = head.
// LDS: P [4][64][72] (36864B) + vT [4][32][64] swz (16384B) = 53248B -> 3 blk/CU
// ============================================================================
__global__ __launch_bounds__(256, 3) void attn_proj_kernel(
    const short* __restrict__ qkv, const float* __restrict__ mask,
    const float* __restrict__ proj_b, const short* __restrict__ projwT,
    const unsigned short* __restrict__ biasBf, float* __restrict__ out)
{
    __shared__ short pool[26624];
    short* P  = pool;           // [4][64][72]
    short* vT = pool + 18432;   // [4][32][64] XOR-swizzled

    const int b = blockIdx.x;
    const int tid = threadIdx.x;
    const int w = tid >> 6, lane = tid & 63, lr = lane & 15, lg = lane >> 4;
    const int h = w;

    const size_t slice = (size_t)(b * 4 + h) * (NT * 32);
    const short* qg = qkv + slice;
    const short* kg = qkv + SQKV + slice;
    const short* vg = qkv + 2 * SQKV + slice;
    short* vTl = vT + h * 2048;
    short* Ph  = P + h * 4608;

    // ---- stage V transposed+swizzled; token slots 49..63 ZEROED (bug fix:
    //      uninitialized LDS here was the R4 NaN source) ----
    for (int i = lane; i < 64 * 8; i += 64) {       // 512 short4 chunks, 8 iters
        int t = i >> 3, d0 = (i & 7) * 4;
        short4 v4 = {0, 0, 0, 0};
        if (t < NT) v4 = *reinterpret_cast<const short4*>(vg + t * 32 + d0);
        vTl[(d0 + 0) * 64 + (t ^ (((d0 + 0) & 7) << 3))] = v4.x;
        vTl[(d0 + 1) * 64 + (t ^ (((d0 + 1) & 7) << 3))] = v4.y;
        vTl[(d0 + 2) * 64 + (t ^ (((d0 + 2) & 7) << 3))] = v4.z;
        vTl[(d0 + 3) * 64 + (t ^ (((d0 + 3) & 7) << 3))] = v4.w;
    }

    // ---- Q/K fragments direct from global (rows >=49 read in-bounds garbage;
    //      fully masked out below) ----
    bf16x8 qa[4], kb[4];
#pragma unroll
    for (int t4 = 0; t4 < 4; ++t4) {
        qa[t4] = *reinterpret_cast<const bf16x8*>(qg + (16 * t4 + lr) * 32 + lg * 8);
        kb[t4] = *reinterpret_cast<const bf16x8*>(kg + (16 * t4 + lr) * 32 + lg * 8);
    }

    const float* maskb = mask + (size_t)b * (NT * NT);
    const unsigned short* biash = biasBf + h * (NT * NT);

    f32x4 oacc[4][2];
#pragma unroll
    for (int mt = 0; mt < 4; ++mt) { oacc[mt][0] = f32x4{0,0,0,0}; oacc[mt][1] = f32x4{0,0,0,0}; }

#pragma unroll
    for (int mt = 0; mt < 4; ++mt) {
        // mask prefetch
        float mreg[4][4];
#pragma unroll
        for (int r = 0; r < 4; ++r) {
            int R = 16 * mt + 4 * lg + r;
#pragma unroll
            for (int ct = 0; ct < 4; ++ct) {
                int c = 16 * ct + lr;
                mreg[r][ct] = (R < NT && c < NT) ? maskb[R * NT + c] : 0.f;
            }
        }

        f32x4 sacc[4];
#pragma unroll
        for (int ct = 0; ct < 4; ++ct) {
            f32x4 z = {0.f, 0.f, 0.f, 0.f};
            sacc[ct] = __builtin_amdgcn_mfma_f32_16x16x32_bf16(qa[mt], kb[ct], z, 0, 0, 0);
        }

        // softmax (no max-sub: valid logits bounded, fp32-exact).
        // Padded rows (R>=49) and cols (c>=49) forced to exact 0 -> no NaN.
#pragma unroll
        for (int r = 0; r < 4; ++r) {
            int R = 16 * mt + 4 * lg + r;
            bool rv = R < NT;
            float e[4], sum;
#pragma unroll
            for (int ct = 0; ct < 4; ++ct) {
                int c = 16 * ct + lr;
                bool cv = c < NT;
                float bval = (rv && cv) ? bf2f(biash[R * NT + c]) : 0.f;
                float sv = sacc[ct][r] + mreg[r][ct] + bval;
                e[ct] = (rv && cv) ? exp2f(sv * LOG2E) : 0.f;
            }
            sum = (e[0] + e[1]) + (e[2] + e[3]);
            sum += __shfl_xor(sum, 1);
            sum += __shfl_xor(sum, 2);
            sum += __shfl_xor(sum, 4);
            sum += __shfl_xor(sum, 8);
            float inv = rv ? (1.0f / sum) : 0.f;
#pragma unroll
            for (int ct = 0; ct < 4; ++ct)
                Ph[R * 72 + 16 * ct + lr] = f2bf(e[ct] * inv);
        }

        // PV for this mt (own-wave P + own-head vT)
        bf16x8 pa0 = *reinterpret_cast<const bf16x8*>(&Ph[(16 * mt + lr) * 72 + lg * 8]);
        bf16x8 pa1 = *reinterpret_cast<const bf16x8*>(&Ph[(16 * mt + lr) * 72 + 32 + lg * 8]);
#pragma unroll
        for (int nt = 0; nt < 2; ++nt) {
            int dl = 16 * nt + lr;
            bf16x8 vb0 = *reinterpret_cast<const bf16x8*>(&vT[h * 2048 + dl * 64 + ((lg * 8) ^ ((dl & 7) << 3))]);
            bf16x8 vb1 = *reinterpret_cast<const bf16x8*>(&vT[h * 2048 + dl * 64 + ((32 + lg * 8) ^ ((dl & 7) << 3))]);
            oacc[mt][nt] = __builtin_amdgcn_mfma_f32_16x16x32_bf16(pa0, vb0, oacc[mt][nt], 0, 0, 0);
            oacc[mt][nt] = __builtin_amdgcn_mfma_f32_16x16x32_bf16(pa1, vb1, oacc[mt][nt], 0, 0, 0);
        }
    }
    __syncthreads();   // #1: all P/vT reads done; pool becomes o

    short* o = pool;   // [64][128] swizzled
#pragma unroll
    for (int mt = 0; mt < 4; ++mt)
#pragma unroll
        for (int nt = 0; nt < 2; ++nt)
#pragma unroll
            for (int r = 0; r < 4; ++r)
                o[swz128(16 * mt + 4 * lg + r, 32 * h + 16 * nt + lr)] = f2bf(oacc[mt][nt][r]);
    __syncthreads();   // #2: o visible

    // ---- proj: wave w -> rows 16w..+16, all 128 cols ----
    bf16x8 ao[4];
#pragma unroll
    for (int kt = 0; kt < 4; ++kt)
        ao[kt] = *reinterpret_cast<const bf16x8*>(&o[swz128(16 * w + lr, kt * 32 + lg * 8)]);
#pragma unroll
    for (int nt = 0; nt < 8; ++nt) {
        f32x4 acc = {0.f, 0.f, 0.f, 0.f};
#pragma unroll
        for (int kt = 0; kt < 4; ++kt) {
            bf16x8 bb = *reinterpret_cast<const bf16x8*>(&projwT[(nt * 16 + lr) * 128 + kt * 32 + lg * 8]);
            acc = __builtin_amdgcn_mfma_f32_16x16x32_bf16(ao[kt], bb, acc, 0, 0, 0);
        }
        int col = nt * 16 + lr;
        float pb = proj_b[col];
#pragma unroll
        for (int r = 0; r < 4; ++r) {
            int row = 16 * w + 4 * lg + r;
            if (row < NT)
                out[((size_t)b * NT + row) * CD + col] = acc[r] + pb;
        }
    }
}

// ============================================================================
// Fallback fused kernel (R3, known-passing) — used only if ws_size too small.
// ============================================================================
constexpr int QK_STRIDE = 72;
constexpr int QK_HEAD   = 64 * QK_STRIDE;
constexpr int VT_BASE   = 4 * QK_HEAD;
constexpr int POOL_SH   = VT_BASE + 4 * 32 * 64;

__global__ __launch_bounds__(512) void winattn_fused_kernel(
    const float* __restrict__ x, const float* __restrict__ mask,
    const float* __restrict__ qkv_b, const float* __restrict__ proj_b,
    const short* __restrict__ qkvwT, const short* __restrict__ projwT,
    const unsigned short* __restrict__ biasBf, float* __restrict__ out)
{
    __shared__ short pool[POOL_SH];
    short* qk = pool;
    short* vT = pool + VT_BASE;

    const int b = blockIdx.x;
    const int tid = threadIdx.x;
    const int w = tid >> 6;
    const int lane = tid & 63;
    const int lr = lane & 15;
    const int lg = lane >> 4;
    const int wr = w >> 1;
    const int wh = w & 1;

    bf16x8 a[4];
    {
        const int arow = 16 * wr + lr;
        const bool avalid = arow < NT;
        const float* xrow = x + (long)b * NT * CD + arow * CD;
#pragma unroll
        for (int kt = 0; kt < 4; ++kt) {
            float4 v0 = {0.f,0.f,0.f,0.f}, v1 = {0.f,0.f,0.f,0.f};
            if (avalid) {
                const float4* p = reinterpret_cast<const float4*>(xrow + kt * 32 + lg * 8);
                v0 = p[0]; v1 = p[1];
            }
            union { unsigned int u[4]; bf16x8 v; } cv;
            cv.u[0] = pk2(v0.x, v0.y); cv.u[1] = pk2(v0.z, v0.w);
            cv.u[2] = pk2(v1.x, v1.y); cv.u[3] = pk2(v1.z, v1.w);
            a[kt] = cv.v;
        }
    }
    {
        int nt0 = wh * 12;
#pragma unroll
        for (int i = 0; i < 12; ++i) {
            int nt = nt0 + i;
            f32x4 acc = {0.f, 0.f, 0.f, 0.f};
#pragma unroll
            for (int kt = 0; kt < 4; ++kt) {
                bf16x8 bb = *reinterpret_cast<const bf16x8*>(&qkvwT[(nt * 16 + lr) * 128 + kt * 32 + lg * 8]);
                acc = __builtin_amdgcn_mfma_f32_16x16x32_bf16(a[kt], bb, acc, 0, 0, 0);
            }
            int s = nt >> 3, hh = (nt >> 1) & 3, d = (nt & 1) * 16 + lr;
            float bias = qkv_b[nt * 16 + lr];
#pragma unroll
            for (int r = 0; r < 4; ++r) {
                int row = 16 * wr + 4 * lg + r;
                float vv = acc[r] + bias;
                if (s == 0)      qk[hh * QK_HEAD + row * QK_STRIDE + d] = f2bf(vv * SCALE);
                else if (s == 1) qk[hh * QK_HEAD + row * QK_STRIDE + 32 + d] = f2bf(vv);
                else             vT[hh * 2048 + d * 64 + (row ^ ((d & 7) << 3))] = f2bf(vv);
            }
        }
    }
    __syncthreads();
    {
        const int hh = wr;
        const int mt0 = wh * 2;
        short* qh = qk + hh * QK_HEAD;
        bf16x8 qa[2], kb[4];
#pragma unroll
        for (int t = 0; t < 2; ++t)
            qa[t] = *reinterpret_cast<const bf16x8*>(&qh[(16 * (mt0 + t) + lr) * QK_STRIDE + lg * 8]);
#pragma unroll
        for (int t = 0; t < 4; ++t)
            kb[t] = *reinterpret_cast<const bf16x8*>(&qh[(16 * t + lr) * QK_STRIDE + 32 + lg * 8]);
        __syncthreads();
        const float* maskb = mask + (long)b * NT * NT;
        const unsigned short* biash = biasBf + hh * NT * NT;
        f32x4 oacc[2][2];
#pragma unroll
        for (int mt2 = 0; mt2 < 2; ++mt2) { oacc[mt2][0] = f32x4{0,0,0,0}; oacc[mt2][1] = f32x4{0,0,0,0}; }
#pragma unroll
        for (int mt2 = 0; mt2 < 2; ++mt2) {
            const int mt = mt0 + mt2;
            float mreg[4][4];
#pragma unroll
            for (int r = 0; r < 4; ++r) {
                int R = 16 * mt + 4 * lg + r;
#pragma unroll
                for (int ct = 0; ct < 4; ++ct) {
                    int c = 16 * ct + lr;
                    mreg[r][ct] = (R < NT && c < NT) ? maskb[R * NT + c] : 0.f;
                }
            }
            f32x4 sacc[4];
#pragma unroll
            for (int ct = 0; ct < 4; ++ct) {
                f32x4 z = {0.f, 0.f, 0.f, 0.f};
                sacc[ct] = __builtin_amdgcn_mfma_f32_16x16x32_bf16(qa[mt2], kb[ct], z, 0, 0, 0);
            }
#pragma unroll
            for (int r = 0; r < 4; ++r) {
                int R = 16 * mt + 4 * lg + r;
                bool rv = R < NT;
                float e[4], sum;
#pragma unroll
                for (int ct = 0; ct < 4; ++ct) {
                    int c = 16 * ct + lr;
                    bool cvv = c < NT;
                    float bval = (rv && cvv) ? bf2f(biash[R * NT + c]) : 0.f;
                    float sv = sacc[ct][r] + mreg[r][ct] + bval;
                    e[ct] = cvv ? exp2f(sv * LOG2E) : 0.f;
                }
                sum = (e[0] + e[1]) + (e[2] + e[3]);
                sum += __shfl_xor(sum, 1);
                sum += __shfl_xor(sum, 2);
                sum += __shfl_xor(sum, 4);
                sum += __shfl_xor(sum, 8);
                float inv = 1.0f / sum;
#pragma unroll
                for (int ct = 0; ct < 4; ++ct)
                    qh[R * QK_STRIDE + 16 * ct + lr] = f2bf(e[ct] * inv);
            }
            bf16x8 pa0 = *reinterpret_cast<const bf16x8*>(&qh[(16 * mt + lr) * QK_STRIDE + lg * 8]);
            bf16x8 pa1 = *reinterpret_cast<const bf16x8*>(&qh[(16 * mt + lr) * QK_STRIDE + 32 + lg * 8]);
#pragma unroll
            for (int nt = 0; nt < 2; ++nt) {
                int dl = 16 * nt + lr;
                bf16x8 vb0 = *reinterpret_cast<const bf16x8*>(&vT[hh * 2048 + dl * 64 + ((lg * 8) ^ ((dl & 7) << 3))]);
                bf16x8 vb1 = *reinterpret_cast<const bf16x8*>(&vT[hh * 2048 + dl * 64 + ((32 + lg * 8) ^ ((dl & 7) << 3))]);
                oacc[mt2][nt] = __builtin_amdgcn_mfma_f32_16x16x32_bf16(pa0, vb0, oacc[mt2][nt], 0, 0, 0);
                oacc[mt2][nt] = __builtin_amdgcn_mfma_f32_16x16x32_bf16(pa1, vb1, oacc[mt2][nt], 0, 0, 0);
            }
        }
        __syncthreads();
        short* o = vT;
#pragma unroll
        for (int mt2 = 0; mt2 < 2; ++mt2)
#pragma unroll
            for (int nt = 0; nt < 2; ++nt)
#pragma unroll
                for (int r = 0; r < 4; ++r)
                    o[swz128(16 * (mt0 + mt2) + 4 * lg + r, 32 * hh + 16 * nt + lr)] = f2bf(oacc[mt2][nt][r]);
    }
    __syncthreads();
    {
        const short* o = vT;
        bf16x8 ao[4];
#pragma unroll
        for (int kt = 0; kt < 4; ++kt)
            ao[kt] = *reinterpret_cast<const bf16x8*>(&o[swz128(16 * wr + lr, kt * 32 + lg * 8)]);
        int n0 = wh * 4;
#pragma unroll
        for (int i = 0; i < 4; ++i) {
            int nt = n0 + i;
            f32x4 acc = {0.f, 0.f, 0.f, 0.f};
#pragma unroll
            for (int kt = 0; kt < 4; ++kt) {
                bf16x8 bb = *reinterpret_cast<const bf16x8*>(&projwT[(nt * 16 + lr) * 128 + kt * 32 + lg * 8]);
                acc = __builtin_amdgcn_mfma_f32_16x16x32_bf16(ao[kt], bb, acc, 0, 0, 0);
            }
            int col = nt * 16 + lr;
            float pb = proj_b[col];
#pragma unroll
            for (int r = 0; r < 4; ++r) {
                int row = 16 * wr + 4 * lg + r;
                if (row < NT)
                    out[((long)b * NT + row) * CD + col] = acc[r] + pb;
            }
        }
    }
}

extern "C" void kernel_launch(void* const* d_in, const int* in_sizes, int n_in,
                              void* d_out, int out_size, void* d_ws, size_t ws_size,
                              hipStream_t stream) {
    const float* x      = (const float*)d_in[0];
    const float* mask   = (const float*)d_in[1];
    const float* qkv_w  = (const float*)d_in[2];
    const float* qkv_b  = (const float*)d_in[3];
    const float* rbt    = (const float*)d_in[4];
    const float* proj_w = (const float*)d_in[5];
    const float* proj_b = (const float*)d_in[6];
    const int*   ridx   = (const int*)d_in[7];
    float* out = (float*)d_out;

    char* ws = (char*)d_ws;
    short* qkvwT  = (short*)(ws + WS_QKVWT);
    short* projwT = (short*)(ws + WS_PROJWT);
    unsigned short* biasBf = (unsigned short*)(ws + WS_BIAS);

    prep_kernel<<<192, 256, 0, stream>>>(qkv_w, proj_w, rbt, ridx, qkvwT, projwT, biasBf);

    if (ws_size >= WS_SPLIT_NEED) {
        short* qkv = (short*)(ws + WS_QKV);
        qkv_gemm_kernel<<<(NB * NT) / 64, 256, 0, stream>>>(x, qkv_b, qkvwT, qkv);
        attn_proj_kernel<<<NB, 256, 0, stream>>>(qkv, mask, proj_b, projwT, biasBf, out);
    } else {
        winattn_fused_kernel<<<NB, 512, 0, stream>>>(x, mask, qkv_b, proj_b, qkvwT, projwT, biasBf, out);
    }
}